// Round 18
// baseline (254.621 us; speedup 1.0000x reference)
//
#include <hip/hip_runtime.h>
#include <math.h>

// Problem constants
#define Bn 4
#define Tn 2048
#define Cn 1024
#define Hn 16
#define HDn 64
#define Mn (Bn * Tn)  // 8192 tokens

typedef unsigned short u16;
typedef unsigned int u32;
typedef __attribute__((ext_vector_type(8))) short bf16x8;        // 8 bf16 = 4 VGPRs
typedef __attribute__((ext_vector_type(8))) unsigned short us8;  // 16B chunk
typedef __attribute__((ext_vector_type(4))) float f32x4;         // 16x16 MFMA acc
typedef __attribute__((ext_vector_type(16))) float f32x16;       // 32x32 MFMA acc
typedef __attribute__((ext_vector_type(4))) unsigned int u32x4;

__device__ __forceinline__ float b2f(u16 u) {
    return __uint_as_float(((u32)u) << 16);
}
__device__ __forceinline__ u16 f2b(float f) {
    u32 u = __float_as_uint(f);
    return (u16)((u + 0x7FFFu + ((u >> 16) & 1u)) >> 16);  // RNE
}
__device__ __forceinline__ u32 cvtpk(float a, float b) {   // {lo:bf16(a), hi:bf16(b)}
    u32 d;
    asm("v_cvt_pk_bf16_f32 %0, %1, %2" : "=v"(d) : "v"(a), "v"(b));
    return d;
}
// v_permlane32_swap_b32: a[32..63] <-> b[0..31]
__device__ __forceinline__ void pswap(u32& a, u32& b) {
    asm("v_permlane32_swap_b32 %0, %1" : "+v"(a), "+v"(b));
}
__device__ __forceinline__ float max3f(float a, float b, float c) {
    float d;
    asm("v_max3_f32 %0, %1, %2, %3" : "=v"(d) : "v"(a), "v"(b), "v"(c));
    return d;
}
#define EXP2R(x) __builtin_amdgcn_exp2f(x)   // raw v_exp_f32 (|x| < 126 here)

// XCD-grouped work id from flat block id (requires gridDim.x % 8 == 0).
__device__ __forceinline__ int xcd_work(int bid, int nwg) {
    return (bid & 7) * (nwg >> 3) + (bid >> 3);
}

// global_load_lds, width 16 (literal size required)
#define GLL(srcp, dstp)                                                     \
    __builtin_amdgcn_global_load_lds(                                       \
        (const __attribute__((address_space(1))) u32*)(srcp),               \
        (__attribute__((address_space(3))) u32*)(dstp), 16, 0, 0)

// counted vmcnt waits (T4): never drain to 0 in the main loop
#define WAITCNT6() asm volatile("s_waitcnt vmcnt(6)" ::: "memory")
#define WAITCNT4() asm volatile("s_waitcnt vmcnt(4)" ::: "memory")
#define WAITCNT0() asm volatile("s_waitcnt vmcnt(0)" ::: "memory")

// ---------------------------------------------------------------------------
// Combined prep kernel (ONE launch):
//   blocks [0,2048)      : x fp32 -> xb bf16 (grid-stride over 2M float4)
//   blocks [2048,5120)   : W_attn [1024,3072] -> WaT [3072,1024] (32x32 tiles)
//   blocks [5120,6144)   : W_proj [1024,1024] -> WpT [1024,1024]
// ---------------------------------------------------------------------------
__global__ __launch_bounds__(256) void prep_kernel(
    const float4* __restrict__ x4, ushort4* __restrict__ xb4, int n4,
    const float* __restrict__ Wa, u16* __restrict__ WaT,
    const float* __restrict__ Wp, u16* __restrict__ WpT)
{
    __shared__ u16 t[32][33];
    const int bid = blockIdx.x;
    if (bid < 2048) {
        for (int i = bid * 256 + threadIdx.x; i < n4; i += 2048 * 256) {
            float4 v = x4[i];
            ushort4 o;
            o.x = f2b(v.x); o.y = f2b(v.y); o.z = f2b(v.z); o.w = f2b(v.w);
            xb4[i] = o;
        }
        return;
    }
    const float* in; u16* out; int Cc, cb, rb;
    if (bid < 5120) {
        const int b2 = bid - 2048;            // 3072 = 96 cols x 32 rows
        in = Wa; out = WaT; Cc = 3 * Cn; cb = b2 % 96; rb = b2 / 96;
    } else {
        const int b3 = bid - 5120;            // 1024 = 32 cols x 32 rows
        in = Wp; out = WpT; Cc = Cn;     cb = b3 & 31; rb = b3 >> 5;
    }
    const int c0 = cb * 32, r0 = rb * 32;
    const int tx = threadIdx.x & 31, ty = threadIdx.x >> 5;  // 32 x 8
    #pragma unroll
    for (int i = 0; i < 32; i += 8)
        t[ty + i][tx] = f2b(in[(size_t)(r0 + ty + i) * Cc + c0 + tx]);
    __syncthreads();
    #pragma unroll
    for (int i = 0; i < 32; i += 8)
        out[(size_t)(c0 + ty + i) * Cn + r0 + tx] = t[tx][ty + i];
}

// ---------------------------------------------------------------------------
// QKV GEMM v7: 128x256 block, BK=32, 4 waves (2Mx2N), wave tile 64x128.
// DOUBLE-buffered LDS (48KB -> 3 blocks/CU, +50% resident waves vs R12's
// 72KB/2-block triple buffer), counted vmcnt(6), TWO barriers per K-step
// (acquire: stage(t) landed everywhere; release: all waves done reading
// buf[t&1] before it is restaged with tile t+2).
// Q/K cols -> qkvb rows; V cols (>=2048) -> vT[b][c][t] transposed.
// Grid 64x12 = 768.
// ---------------------------------------------------------------------------
__global__ __launch_bounds__(256, 3) void gemm_qkv_kernel(
    const u16* __restrict__ A, const u16* __restrict__ BT,
    const float* __restrict__ bias,
    u16* __restrict__ outb, u16* __restrict__ vTout,
    int N, int K, int nx)
{
    __shared__ u16 Al[2][128 * 32];   // 8KB per buffer
    __shared__ u16 Bl[2][256 * 32];   // 16KB per buffer

    const int tid = threadIdx.x;
    const int workid = xcd_work(blockIdx.x, gridDim.x);
    const int brow = (workid / nx) * 128;
    const int bcol = (workid % nx) * 256;
    const int w  = tid >> 6;
    const int wr = w >> 1, wc = w & 1;
    const int l  = tid & 63;
    const int lr = l & 15;
    const int lk = (l >> 4) << 3;

    const int sr = l >> 2;
    const int sc = (l & 3) << 3;

    f32x4 acc[4][8];
    #pragma unroll
    for (int m = 0; m < 4; ++m)
        #pragma unroll
        for (int n = 0; n < 8; ++n) acc[m][n] = (f32x4){0.f, 0.f, 0.f, 0.f};

    #define STAGE_G(k0, bufi)                                                   \
        do {                                                                    \
            GLL(&A [(size_t)(brow + 32 * w +      sr) * K + (k0) + sc],         \
                &Al[bufi][(32 * w) * 32]);                                      \
            GLL(&A [(size_t)(brow + 32 * w + 16 + sr) * K + (k0) + sc],         \
                &Al[bufi][(32 * w + 16) * 32]);                                 \
            GLL(&BT[(size_t)(bcol + 64 * w +      sr) * K + (k0) + sc],         \
                &Bl[bufi][(64 * w) * 32]);                                      \
            GLL(&BT[(size_t)(bcol + 64 * w + 16 + sr) * K + (k0) + sc],         \
                &Bl[bufi][(64 * w + 16) * 32]);                                 \
            GLL(&BT[(size_t)(bcol + 64 * w + 32 + sr) * K + (k0) + sc],         \
                &Bl[bufi][(64 * w + 32) * 32]);                                 \
            GLL(&BT[(size_t)(bcol + 64 * w + 48 + sr) * K + (k0) + sc],         \
                &Bl[bufi][(64 * w + 48) * 32]);                                 \
        } while (0)

    const int T = K >> 5;
    STAGE_G(0, 0);
    STAGE_G(32, 1);

    for (int t = 0; t < T; ++t) {
        if (t < T - 1) WAITCNT6();      // own stage(t) landed; t+1 in flight
        else           WAITCNT0();      // final tile: full drain
        __builtin_amdgcn_s_barrier();   // acquire: all waves' stage(t) landed

        const int cur = t & 1;
        bf16x8 a[4], b[8];
        #pragma unroll
        for (int m = 0; m < 4; ++m)
            a[m] = *(const bf16x8*)&Al[cur][(wr * 64 + m * 16 + lr) * 32 + lk];
        #pragma unroll
        for (int n = 0; n < 8; ++n)
            b[n] = *(const bf16x8*)&Bl[cur][(wc * 128 + n * 16 + lr) * 32 + lk];

        __builtin_amdgcn_s_setprio(1);
        #pragma unroll
        for (int m = 0; m < 4; ++m)
            #pragma unroll
            for (int n = 0; n < 8; ++n)
                acc[m][n] = __builtin_amdgcn_mfma_f32_16x16x32_bf16(
                    a[m], b[n], acc[m][n], 0, 0, 0);
        __builtin_amdgcn_s_setprio(0);

        __builtin_amdgcn_s_barrier();   // release: all waves done reading cur
        if (t + 2 < T) STAGE_G((t + 2) << 5, cur);
    }
    #undef STAGE_G

    // Epilogue. C/D layout: col = lane&15, row = (lane>>4)*4 + reg.
    const int orow0 = brow + wr * 64 + ((l >> 4) << 2);
    const int ocol0 = bcol + wc * 128 + lr;
    if (bcol >= 2048) {
        #pragma unroll
        for (int n = 0; n < 8; ++n) {
            const int c = ocol0 + n * 16 - 2048;
            const float bv = bias[ocol0 + n * 16];
            #pragma unroll
            for (int m = 0; m < 4; ++m) {
                const int row0 = orow0 + m * 16;
                const int bb = row0 >> 11, t0 = row0 & 2047;
                ushort4 pk;
                pk.x = f2b(acc[m][n][0] + bv);
                pk.y = f2b(acc[m][n][1] + bv);
                pk.z = f2b(acc[m][n][2] + bv);
                pk.w = f2b(acc[m][n][3] + bv);
                *(ushort4*)&vTout[((size_t)bb * Cn + c) * Tn + t0] = pk;
            }
        }
    } else {
        #pragma unroll
        for (int n = 0; n < 8; ++n) {
            const int col = ocol0 + n * 16;
            const float bv = bias[col];
            #pragma unroll
            for (int m = 0; m < 4; ++m) {
                #pragma unroll
                for (int r = 0; r < 4; ++r) {
                    const int row = orow0 + m * 16 + r;
                    outb[(size_t)row * N + col] = f2b(acc[m][n][r] + bv);
                }
            }
        }
    }
}

// ---------------------------------------------------------------------------
// Proj GEMM (R12/R16-verified): 128x128, BK=32, 4 waves, 3 buffers, counted
// vmcnt(4). f32 out. Grid 8x64 = 512 (2 blocks/CU).
// ---------------------------------------------------------------------------
__global__ __launch_bounds__(256) void gemm_proj_kernel(
    const u16* __restrict__ A, const u16* __restrict__ BT,
    const float* __restrict__ bias, float* __restrict__ outf,
    int N, int K, int nx)
{
    __shared__ u16 Al[3][128 * 32];
    __shared__ u16 Bl[3][128 * 32];

    const int tid = threadIdx.x;
    const int workid = xcd_work(blockIdx.x, gridDim.x);
    const int brow = (workid / nx) * 128;
    const int bcol = (workid % nx) * 128;
    const int w  = tid >> 6;
    const int wr = w >> 1, wc = w & 1;
    const int l  = tid & 63;
    const int lr = l & 15;
    const int lk = (l >> 4) << 3;

    const int r0s = tid >> 2,            c0s = (tid & 3) << 3;
    const int r1s = (256 + tid) >> 2;
    const int d0s = (tid & 192) * 8;
    const int d1s = (256 + (tid & 192)) * 8;

    f32x4 acc[4][4];
    #pragma unroll
    for (int m = 0; m < 4; ++m)
        #pragma unroll
        for (int n = 0; n < 4; ++n) acc[m][n] = (f32x4){0.f, 0.f, 0.f, 0.f};

    #define STAGE_P(k0, bufi)                                                \
        do {                                                                 \
            GLL(&A [(size_t)(brow + r0s) * K + (k0) + c0s], &Al[bufi][d0s]); \
            GLL(&BT[(size_t)(bcol + r0s) * K + (k0) + c0s], &Bl[bufi][d0s]); \
            GLL(&A [(size_t)(brow + r1s) * K + (k0) + c0s], &Al[bufi][d1s]); \
            GLL(&BT[(size_t)(bcol + r1s) * K + (k0) + c0s], &Bl[bufi][d1s]); \
        } while (0)

    const int T = K >> 5;
    STAGE_P(0, 0);
    STAGE_P(32, 1);

    int cur = 0;
    for (int t = 0; t < T; ++t) {
        if (t < T - 1) WAITCNT4();
        else           WAITCNT0();
        __builtin_amdgcn_s_barrier();

        if (t + 2 < T) {
            const int nb = cur + 2 >= 3 ? cur - 1 : cur + 2;
            STAGE_P((t + 2) << 5, nb);
        }

        bf16x8 a[4], b[4];
        #pragma unroll
        for (int m = 0; m < 4; ++m)
            a[m] = *(const bf16x8*)&Al[cur][(wr * 64 + m * 16 + lr) * 32 + lk];
        #pragma unroll
        for (int n = 0; n < 4; ++n)
            b[n] = *(const bf16x8*)&Bl[cur][(wc * 64 + n * 16 + lr) * 32 + lk];

        __builtin_amdgcn_s_setprio(1);
        #pragma unroll
        for (int m = 0; m < 4; ++m)
            #pragma unroll
            for (int n = 0; n < 4; ++n)
                acc[m][n] = __builtin_amdgcn_mfma_f32_16x16x32_bf16(
                    a[m], b[n], acc[m][n], 0, 0, 0);
        __builtin_amdgcn_s_setprio(0);

        cur = cur == 2 ? 0 : cur + 1;
    }
    #undef STAGE_P

    const int orow0 = brow + wr * 64 + ((l >> 4) << 2);
    const int ocol0 = bcol + wc * 64 + lr;
    #pragma unroll
    for (int n = 0; n < 4; ++n) {
        const int col = ocol0 + n * 16;
        const float bv = bias[col];
        #pragma unroll
        for (int m = 0; m < 4; ++m) {
            #pragma unroll
            for (int r = 0; r < 4; ++r) {
                const int row = orow0 + m * 16 + r;
                outf[(size_t)row * N + col] = acc[m][n][r] + bv;
            }
        }
    }
}

// ---------------------------------------------------------------------------
// MFMA flash attention v8 (causal) - R12/R16-verified exact.
// ---------------------------------------------------------------------------
__global__ __launch_bounds__(256, 2) void attn_mfma8_kernel(
    const u16* __restrict__ qkvb, const u16* __restrict__ vT,
    u16* __restrict__ yb)
{
    __shared__ u16 Kb[3][64 * 64];   // [k-row][d-chunk swizzled]
    __shared__ u16 Vb[3][64 * 64];   // [d-row][k-chunk swizzled]

    const int tid = threadIdx.x;
    const int w   = tid >> 6;        // wave 0..3
    const int l   = tid & 63;
    const int q31 = l & 31;          // q (QK^T B-col) / d (PV B-col)
    const int hi  = l >> 5;
    const int work = xcd_work(blockIdx.x, 512);
    const int pr  = work & 7;        // pair index 0..7
    const int bh  = work >> 3;       // 8 bh per XCD
    const int b   = bh >> 4, h = bh & 15;

    const float S2 = 0.18033688f;    // 0.125 * log2(e)

    const u16* Kg = qkvb + (size_t)(b * Tn) * (3 * Cn) + Cn + h * HDn;
    const u16* Vg = vT + (size_t)bh * HDn * Tn;

    const int srow = l >> 3;                   // staging row 0..7
    const int schk = ((l & 7) ^ srow) << 3;    // swizzled source chunk (u16)
    const int rloc = w * 16;                   // wave's staging row slice
    const int rsw8 = q31 & 7;                  // read-side XOR key (chunk idx)

    #define STAGE_A(kt, bufi)                                                  \
        do {                                                                   \
            _Pragma("unroll")                                                  \
            for (int jc = 0; jc < 2; ++jc) {                                   \
                const int rr = rloc + jc * 8;                                  \
                GLL(Kg + (size_t)((kt) * 64 + rr + srow) * (3 * Cn) + schk,    \
                    &Kb[bufi][rr * 64]);                                       \
                GLL(Vg + (size_t)(rr + srow) * Tn + (kt) * 64 + schk,          \
                    &Vb[bufi][rr * 64]);                                       \
            }                                                                  \
        } while (0)

    #pragma unroll 1
    for (int half = 0; half < 2; ++half) {
        const int qt = half ? (15 - pr) : pr;   // 128-row tile index
        const int ktmax = 2 * qt + 2;
        const int qrow0 = qt * 128 + w * 32;    // wave's first q row
        const int qglob = qrow0 + q31;          // this lane's q row

        // Q B-frags: qf[c] = Q[qglob][c*16 + hi*8 .. +7]
        const u16* Qp = qkvb + (size_t)(b * Tn + qglob) * (3 * Cn)
                        + h * HDn + hi * 8;
        bf16x8 qf[4];
        #pragma unroll
        for (int c = 0; c < 4; ++c) qf[c] = *(const bf16x8*)(Qp + c * 16);

        f32x16 O0, O1;
        #pragma unroll
        for (int r = 0; r < 16; ++r) { O0[r] = 0.f; O1[r] = 0.f; }
        float m = -INFINITY, ls = 0.f;

        STAGE_A(0, 0);
        STAGE_A(1, 1);

        int cur = 0;
        for (int kt = 0; kt < ktmax; ++kt) {
            if (kt < ktmax - 1) WAITCNT4();
            else                WAITCNT0();
            __builtin_amdgcn_s_barrier();

            if (kt + 2 < ktmax) {
                const int nb = cur + 2 >= 3 ? cur - 1 : cur + 2;
                STAGE_A(kt + 2, nb);
            }
            const u16* Kc = Kb[cur];
            const u16* Vc = Vb[cur];

            if (kt * 64 <= qrow0 + 31) {   // wave has unmasked work
                // S^T = K Q^T : two 32x32 tiles (k 0..31, 32..63)
                f32x16 S0, S1;
                #pragma unroll
                for (int r = 0; r < 16; ++r) { S0[r] = 0.f; S1[r] = 0.f; }
                __builtin_amdgcn_s_setprio(1);
                #pragma unroll
                for (int c = 0; c < 4; ++c) {
                    const int co = ((2 * c + hi) ^ rsw8) << 3;
                    const bf16x8 k0 = *(const bf16x8*)&Kc[q31 * 64 + co];
                    const bf16x8 k1 = *(const bf16x8*)&Kc[(32 + q31) * 64 + co];
                    S0 = __builtin_amdgcn_mfma_f32_32x32x16_bf16(k0, qf[c], S0, 0, 0, 0);
                    S1 = __builtin_amdgcn_mfma_f32_32x32x16_bf16(k1, qf[c], S1, 0, 0, 0);
                }
                __builtin_amdgcn_s_setprio(0);

                // causal mask (diagonal-straddling steps only)
                if (kt * 64 + 63 > qrow0) {
                    #pragma unroll
                    for (int r = 0; r < 16; ++r) {
                        const int kl = kt * 64 + (r & 3) + 8 * (r >> 2) + 4 * hi;
                        if (kl > qglob)      S0[r] = -INFINITY;
                        if (kl + 32 > qglob) S1[r] = -INFINITY;
                    }
                }

                // row max: v_max3 tree (depth 4) + 1 cross-half shuffle
                float a0 = max3f(S0[0],  S0[1],  S0[2]);
                float a1 = max3f(S0[3],  S0[4],  S0[5]);
                float a2 = max3f(S0[6],  S0[7],  S0[8]);
                float a3 = max3f(S0[9],  S0[10], S0[11]);
                float a4 = max3f(S0[12], S0[13], S0[14]);
                float a5 = max3f(S0[15], S1[0],  S1[1]);
                float a6 = max3f(S1[2],  S1[3],  S1[4]);
                float a7 = max3f(S1[5],  S1[6],  S1[7]);
                float a8 = max3f(S1[8],  S1[9],  S1[10]);
                float a9 = max3f(S1[11], S1[12], S1[13]);
                float aA = fmaxf(S1[14], S1[15]);
                float b0 = max3f(a0, a1, a2);
                float b1 = max3f(a3, a4, a5);
                float b2 = max3f(a6, a7, a8);
                float b3 = fmaxf(a9, aA);
                float mt = fmaxf(fmaxf(b0, b1), fmaxf(b2, b3));
                mt = fmaxf(mt, __shfl_xor(mt, 32));

                // defer-max (first active step always triggers: m = -inf)
                float lscale = 1.f;
                if (__any(mt > m + 64.f)) {
                    const float mn = fmaxf(m, mt);
                    const float alpha = EXP2R((m - mn) * S2);
                    m = mn; lscale = alpha;
                    #pragma unroll
                    for (int r = 0; r < 16; ++r) {
                        const int qloc = (r & 3) + 8 * (r >> 2) + 4 * hi;
                        const float ar = __shfl(alpha, qloc);
                        O0[r] *= ar; O1[r] *= ar;
                    }
                }

                // P = exp2(S*S2 - m*S2) via fmaf + raw v_exp_f32
                const float nms2 = -m * S2;
                float lt0 = 0.f, lt1 = 0.f;
                u32 w0[8], w1[8];
                #pragma unroll
                for (int i = 0; i < 8; ++i) {
                    const float p0 = EXP2R(fmaf(S0[2 * i],     S2, nms2));
                    const float p1 = EXP2R(fmaf(S0[2 * i + 1], S2, nms2));
                    const float p2 = EXP2R(fmaf(S1[2 * i],     S2, nms2));
                    const float p3 = EXP2R(fmaf(S1[2 * i + 1], S2, nms2));
                    lt0 += (p0 + p1);
                    lt1 += (p2 + p3);
                    w0[i] = cvtpk(p0, p1);
                    w1[i] = cvtpk(p2, p3);
                }
                float lt = lt0 + lt1;
                lt += __shfl_xor(lt, 32);
                ls = ls * lscale + lt;

                // O += P @ V : assemble A-frags via permlane32_swap, B from Vs
                __builtin_amdgcn_s_setprio(1);
                #pragma unroll
                for (int t2 = 0; t2 < 2; ++t2) {
                    #pragma unroll
                    for (int c1 = 0; c1 < 2; ++c1) {
                        u32 a0w = t2 ? w1[4 * c1 + 0] : w0[4 * c1 + 0];
                        u32 b0w = t2 ? w1[4 * c1 + 2] : w0[4 * c1 + 2];
                        u32 a1w = t2 ? w1[4 * c1 + 1] : w0[4 * c1 + 1];
                        u32 b1w = t2 ? w1[4 * c1 + 3] : w0[4 * c1 + 3];
                        pswap(a0w, b0w);   // -> frag words 0 and 2
                        pswap(a1w, b1w);   // -> frag words 1 and 3
                        u32x4 fr; fr.x = a0w; fr.y = a1w; fr.z = b0w; fr.w = b1w;
                        const bf16x8 pf = __builtin_bit_cast(bf16x8, fr);
                        const int c = t2 * 2 + c1;
                        const int co = ((2 * c + hi) ^ rsw8) << 3;
                        const bf16x8 v0 = *(const bf16x8*)&Vc[q31 * 64 + co];
                        const bf16x8 v1 = *(const bf16x8*)&Vc[(32 + q31) * 64 + co];
                        O0 = __builtin_amdgcn_mfma_f32_32x32x16_bf16(pf, v0, O0, 0, 0, 0);
                        O1 = __builtin_amdgcn_mfma_f32_32x32x16_bf16(pf, v1, O1, 0, 0, 0);
                    }
                }
                __builtin_amdgcn_s_setprio(0);
            }

            cur = cur == 2 ? 0 : cur + 1;
        }

        // all waves done with LDS before next half's prologue restages
        __builtin_amdgcn_s_barrier();

        // epilogue: O row r -> q = qrow0 + (r&3)+8*(r>>2)+4*hi, col = d
        #pragma unroll
        for (int r = 0; r < 16; ++r) {
            const int qloc = (r & 3) + 8 * (r >> 2) + 4 * hi;
            const float inv = __builtin_amdgcn_rcpf(__shfl(ls, qloc));
            u16* yp = yb + (size_t)(b * Tn + qrow0 + qloc) * Cn + h * HDn + q31;
            yp[0]  = f2b(O0[r] * inv);
            yp[32] = f2b(O1[r] * inv);
        }
    }
    #undef STAGE_A
}

// ---------------------------------------------------------------------------
extern "C" void kernel_launch(void* const* d_in, const int* in_sizes, int n_in,
                              void* d_out, int out_size, void* d_ws, size_t ws_size,
                              hipStream_t stream)
{
    const float* x      = (const float*)d_in[0];
    const float* W_attn = (const float*)d_in[1];
    const float* b_attn = (const float*)d_in[2];
    const float* W_proj = (const float*)d_in[3];
    const float* b_proj = (const float*)d_in[4];
    float* out = (float*)d_out;

    // Workspace (bf16): xb | WaT | WpT | qkvb | yb | vT  (~108 MB)
    u16* xb   = (u16*)d_ws;
    u16* WaT  = xb   + (size_t)Mn * Cn;
    u16* WpT  = WaT  + (size_t)3 * Cn * Cn;
    u16* qkvb = WpT  + (size_t)Cn * Cn;
    u16* yb   = qkvb + (size_t)Mn * 3 * Cn;
    u16* vT   = yb   + (size_t)Mn * Cn;

    // one fused prep launch: x->bf16 convert + both weight transposes
    prep_kernel<<<6144, 256, 0, stream>>>(
        (const float4*)x, (ushort4*)xb, Mn * Cn / 4,
        W_attn, WaT, W_proj, WpT);

    // qkv = x @ W_attn + b_attn; Q/K -> qkvb rows, V -> vT (fused transpose)
    gemm_qkv_kernel<<<64 * 12, 256, 0, stream>>>(
        xb, WaT, b_attn, qkvb, vT, 3 * Cn, Cn, 12);

    // causal MFMA attention -> yb (bf16); grid 512 paired, XCD-grouped
    attn_mfma8_kernel<<<512, 256, 0, stream>>>(qkvb, vT, yb);

    // out = y @ W_proj + b_proj (f32 out); grid 512 (2 blocks/CU)
    gemm_proj_kernel<<<8 * 64, 256, 0, stream>>>(
        yb, WpT, b_proj, out, Cn, Cn, 8);
}

// Round 19
// 175.895 us; speedup vs baseline: 1.4476x; 1.4476x over previous
//
#include <hip/hip_runtime.h>
#include <math.h>

// Problem constants
#define Bn 4
#define Tn 2048
#define Cn 1024
#define Hn 16
#define HDn 64
#define Mn (Bn * Tn)  // 8192 tokens

typedef unsigned short u16;
typedef unsigned int u32;
typedef __attribute__((ext_vector_type(8))) short bf16x8;        // 8 bf16 = 4 VGPRs
typedef __attribute__((ext_vector_type(8))) unsigned short us8;  // 16B chunk
typedef __attribute__((ext_vector_type(4))) float f32x4;         // 16x16 MFMA acc
typedef __attribute__((ext_vector_type(16))) float f32x16;       // 32x32 MFMA acc
typedef __attribute__((ext_vector_type(4))) unsigned int u32x4;

__device__ __forceinline__ float b2f(u16 u) {
    return __uint_as_float(((u32)u) << 16);
}
__device__ __forceinline__ u16 f2b(float f) {
    u32 u = __float_as_uint(f);
    return (u16)((u + 0x7FFFu + ((u >> 16) & 1u)) >> 16);  // RNE
}
__device__ __forceinline__ u32 cvtpk(float a, float b) {   // {lo:bf16(a), hi:bf16(b)}
    u32 d;
    asm("v_cvt_pk_bf16_f32 %0, %1, %2" : "=v"(d) : "v"(a), "v"(b));
    return d;
}
// v_permlane32_swap_b32: a[32..63] <-> b[0..31]
__device__ __forceinline__ void pswap(u32& a, u32& b) {
    asm("v_permlane32_swap_b32 %0, %1" : "+v"(a), "+v"(b));
}
__device__ __forceinline__ float max3f(float a, float b, float c) {
    float d;
    asm("v_max3_f32 %0, %1, %2, %3" : "=v"(d) : "v"(a), "v"(b), "v"(c));
    return d;
}
#define EXP2R(x) __builtin_amdgcn_exp2f(x)   // raw v_exp_f32 (|x| < 126 here)

// XCD-grouped work id from flat block id (requires gridDim.x % 8 == 0).
__device__ __forceinline__ int xcd_work(int bid, int nwg) {
    return (bid & 7) * (nwg >> 3) + (bid >> 3);
}

// global_load_lds, width 16 (literal size required)
#define GLL(srcp, dstp)                                                     \
    __builtin_amdgcn_global_load_lds(                                       \
        (const __attribute__((address_space(1))) u32*)(srcp),               \
        (__attribute__((address_space(3))) u32*)(dstp), 16, 0, 0)

// counted vmcnt waits (T4): never drain to 0 in the main loop
#define WAITCNT6() asm volatile("s_waitcnt vmcnt(6)" ::: "memory")
#define WAITCNT4() asm volatile("s_waitcnt vmcnt(4)" ::: "memory")
#define WAITCNT0() asm volatile("s_waitcnt vmcnt(0)" ::: "memory")

// ---------------------------------------------------------------------------
// Combined prep kernel (ONE launch):
//   blocks [0,2048)      : x fp32 -> xb bf16 (grid-stride over 2M float4)
//   blocks [2048,5120)   : W_attn [1024,3072] -> WaT [3072,1024] (32x32 tiles)
//   blocks [5120,6144)   : W_proj [1024,1024] -> WpT [1024,1024]
// ---------------------------------------------------------------------------
__global__ __launch_bounds__(256) void prep_kernel(
    const float4* __restrict__ x4, ushort4* __restrict__ xb4, int n4,
    const float* __restrict__ Wa, u16* __restrict__ WaT,
    const float* __restrict__ Wp, u16* __restrict__ WpT)
{
    __shared__ u16 t[32][33];
    const int bid = blockIdx.x;
    if (bid < 2048) {
        for (int i = bid * 256 + threadIdx.x; i < n4; i += 2048 * 256) {
            float4 v = x4[i];
            ushort4 o;
            o.x = f2b(v.x); o.y = f2b(v.y); o.z = f2b(v.z); o.w = f2b(v.w);
            xb4[i] = o;
        }
        return;
    }
    const float* in; u16* out; int Cc, cb, rb;
    if (bid < 5120) {
        const int b2 = bid - 2048;            // 3072 = 96 cols x 32 rows
        in = Wa; out = WaT; Cc = 3 * Cn; cb = b2 % 96; rb = b2 / 96;
    } else {
        const int b3 = bid - 5120;            // 1024 = 32 cols x 32 rows
        in = Wp; out = WpT; Cc = Cn;     cb = b3 & 31; rb = b3 >> 5;
    }
    const int c0 = cb * 32, r0 = rb * 32;
    const int tx = threadIdx.x & 31, ty = threadIdx.x >> 5;  // 32 x 8
    #pragma unroll
    for (int i = 0; i < 32; i += 8)
        t[ty + i][tx] = f2b(in[(size_t)(r0 + ty + i) * Cc + c0 + tx]);
    __syncthreads();
    #pragma unroll
    for (int i = 0; i < 32; i += 8)
        out[(size_t)(c0 + ty + i) * Cn + r0 + tx] = t[tx][ty + i];
}

// ---------------------------------------------------------------------------
// QKV GEMM (R12/R17-verified, ~84us): 128x256 block, BK=32, 4 waves (2Mx2N),
// wave tile 64x128. Triple-buffered LDS, counted vmcnt(6), one s_barrier per
// K-step. Q/K cols -> qkvb rows; V cols (>=2048) -> vT[b][c][t] transposed.
// Grid 64x12 = 768.
// ---------------------------------------------------------------------------
__global__ __launch_bounds__(256, 2) void gemm_qkv_kernel(
    const u16* __restrict__ A, const u16* __restrict__ BT,
    const float* __restrict__ bias,
    u16* __restrict__ outb, u16* __restrict__ vTout,
    int N, int K, int nx)
{
    __shared__ u16 Al[3][128 * 32];
    __shared__ u16 Bl[3][256 * 32];

    const int tid = threadIdx.x;
    const int workid = xcd_work(blockIdx.x, gridDim.x);
    const int brow = (workid / nx) * 128;
    const int bcol = (workid % nx) * 256;
    const int w  = tid >> 6;
    const int wr = w >> 1, wc = w & 1;
    const int l  = tid & 63;
    const int lr = l & 15;
    const int lk = (l >> 4) << 3;

    const int sr = l >> 2;
    const int sc = (l & 3) << 3;

    f32x4 acc[4][8];
    #pragma unroll
    for (int m = 0; m < 4; ++m)
        #pragma unroll
        for (int n = 0; n < 8; ++n) acc[m][n] = (f32x4){0.f, 0.f, 0.f, 0.f};

    #define STAGE_G(k0, bufi)                                                   \
        do {                                                                    \
            GLL(&A [(size_t)(brow + 32 * w +      sr) * K + (k0) + sc],         \
                &Al[bufi][(32 * w) * 32]);                                      \
            GLL(&A [(size_t)(brow + 32 * w + 16 + sr) * K + (k0) + sc],         \
                &Al[bufi][(32 * w + 16) * 32]);                                 \
            GLL(&BT[(size_t)(bcol + 64 * w +      sr) * K + (k0) + sc],         \
                &Bl[bufi][(64 * w) * 32]);                                      \
            GLL(&BT[(size_t)(bcol + 64 * w + 16 + sr) * K + (k0) + sc],         \
                &Bl[bufi][(64 * w + 16) * 32]);                                 \
            GLL(&BT[(size_t)(bcol + 64 * w + 32 + sr) * K + (k0) + sc],         \
                &Bl[bufi][(64 * w + 32) * 32]);                                 \
            GLL(&BT[(size_t)(bcol + 64 * w + 48 + sr) * K + (k0) + sc],         \
                &Bl[bufi][(64 * w + 48) * 32]);                                 \
        } while (0)

    const int T = K >> 5;
    STAGE_G(0, 0);
    STAGE_G(32, 1);

    int cur = 0;
    for (int t = 0; t < T; ++t) {
        if (t < T - 1) WAITCNT6();
        else           WAITCNT0();
        __builtin_amdgcn_s_barrier();

        if (t + 2 < T) {
            const int nb = cur + 2 >= 3 ? cur - 1 : cur + 2;
            STAGE_G((t + 2) << 5, nb);
        }

        bf16x8 a[4], b[8];
        #pragma unroll
        for (int m = 0; m < 4; ++m)
            a[m] = *(const bf16x8*)&Al[cur][(wr * 64 + m * 16 + lr) * 32 + lk];
        #pragma unroll
        for (int n = 0; n < 8; ++n)
            b[n] = *(const bf16x8*)&Bl[cur][(wc * 128 + n * 16 + lr) * 32 + lk];

        __builtin_amdgcn_s_setprio(1);
        #pragma unroll
        for (int m = 0; m < 4; ++m)
            #pragma unroll
            for (int n = 0; n < 8; ++n)
                acc[m][n] = __builtin_amdgcn_mfma_f32_16x16x32_bf16(
                    a[m], b[n], acc[m][n], 0, 0, 0);
        __builtin_amdgcn_s_setprio(0);

        cur = cur == 2 ? 0 : cur + 1;
    }
    #undef STAGE_G

    // Epilogue. C/D layout: col = lane&15, row = (lane>>4)*4 + reg.
    const int orow0 = brow + wr * 64 + ((l >> 4) << 2);
    const int ocol0 = bcol + wc * 128 + lr;
    if (bcol >= 2048) {
        #pragma unroll
        for (int n = 0; n < 8; ++n) {
            const int c = ocol0 + n * 16 - 2048;
            const float bv = bias[ocol0 + n * 16];
            #pragma unroll
            for (int m = 0; m < 4; ++m) {
                const int row0 = orow0 + m * 16;
                const int bb = row0 >> 11, t0 = row0 & 2047;
                ushort4 pk;
                pk.x = f2b(acc[m][n][0] + bv);
                pk.y = f2b(acc[m][n][1] + bv);
                pk.z = f2b(acc[m][n][2] + bv);
                pk.w = f2b(acc[m][n][3] + bv);
                *(ushort4*)&vTout[((size_t)bb * Cn + c) * Tn + t0] = pk;
            }
        }
    } else {
        #pragma unroll
        for (int n = 0; n < 8; ++n) {
            const int col = ocol0 + n * 16;
            const float bv = bias[col];
            #pragma unroll
            for (int m = 0; m < 4; ++m) {
                #pragma unroll
                for (int r = 0; r < 4; ++r) {
                    const int row = orow0 + m * 16 + r;
                    outb[(size_t)row * N + col] = f2b(acc[m][n][r] + bv);
                }
            }
        }
    }
}

// ---------------------------------------------------------------------------
// Proj GEMM (R12/R17-verified): 128x128, BK=32, 4 waves, 3 buffers, counted
// vmcnt(4). f32 out. Grid 8x64 = 512 (2 blocks/CU).
// ---------------------------------------------------------------------------
__global__ __launch_bounds__(256) void gemm_proj_kernel(
    const u16* __restrict__ A, const u16* __restrict__ BT,
    const float* __restrict__ bias, float* __restrict__ outf,
    int N, int K, int nx)
{
    __shared__ u16 Al[3][128 * 32];
    __shared__ u16 Bl[3][128 * 32];

    const int tid = threadIdx.x;
    const int workid = xcd_work(blockIdx.x, gridDim.x);
    const int brow = (workid / nx) * 128;
    const int bcol = (workid % nx) * 128;
    const int w  = tid >> 6;
    const int wr = w >> 1, wc = w & 1;
    const int l  = tid & 63;
    const int lr = l & 15;
    const int lk = (l >> 4) << 3;

    const int r0s = tid >> 2,            c0s = (tid & 3) << 3;
    const int r1s = (256 + tid) >> 2;
    const int d0s = (tid & 192) * 8;
    const int d1s = (256 + (tid & 192)) * 8;

    f32x4 acc[4][4];
    #pragma unroll
    for (int m = 0; m < 4; ++m)
        #pragma unroll
        for (int n = 0; n < 4; ++n) acc[m][n] = (f32x4){0.f, 0.f, 0.f, 0.f};

    #define STAGE_P(k0, bufi)                                                \
        do {                                                                 \
            GLL(&A [(size_t)(brow + r0s) * K + (k0) + c0s], &Al[bufi][d0s]); \
            GLL(&BT[(size_t)(bcol + r0s) * K + (k0) + c0s], &Bl[bufi][d0s]); \
            GLL(&A [(size_t)(brow + r1s) * K + (k0) + c0s], &Al[bufi][d1s]); \
            GLL(&BT[(size_t)(bcol + r1s) * K + (k0) + c0s], &Bl[bufi][d1s]); \
        } while (0)

    const int T = K >> 5;
    STAGE_P(0, 0);
    STAGE_P(32, 1);

    int cur = 0;
    for (int t = 0; t < T; ++t) {
        if (t < T - 1) WAITCNT4();
        else           WAITCNT0();
        __builtin_amdgcn_s_barrier();

        if (t + 2 < T) {
            const int nb = cur + 2 >= 3 ? cur - 1 : cur + 2;
            STAGE_P((t + 2) << 5, nb);
        }

        bf16x8 a[4], b[4];
        #pragma unroll
        for (int m = 0; m < 4; ++m)
            a[m] = *(const bf16x8*)&Al[cur][(wr * 64 + m * 16 + lr) * 32 + lk];
        #pragma unroll
        for (int n = 0; n < 4; ++n)
            b[n] = *(const bf16x8*)&Bl[cur][(wc * 64 + n * 16 + lr) * 32 + lk];

        __builtin_amdgcn_s_setprio(1);
        #pragma unroll
        for (int m = 0; m < 4; ++m)
            #pragma unroll
            for (int n = 0; n < 4; ++n)
                acc[m][n] = __builtin_amdgcn_mfma_f32_16x16x32_bf16(
                    a[m], b[n], acc[m][n], 0, 0, 0);
        __builtin_amdgcn_s_setprio(0);

        cur = cur == 2 ? 0 : cur + 1;
    }
    #undef STAGE_P

    const int orow0 = brow + wr * 64 + ((l >> 4) << 2);
    const int ocol0 = bcol + wc * 64 + lr;
    #pragma unroll
    for (int n = 0; n < 4; ++n) {
        const int col = ocol0 + n * 16;
        const float bv = bias[col];
        #pragma unroll
        for (int m = 0; m < 4; ++m) {
            #pragma unroll
            for (int r = 0; r < 4; ++r) {
                const int row = orow0 + m * 16 + r;
                outf[(size_t)row * N + col] = acc[m][n][r] + bv;
            }
        }
    }
}

// ---------------------------------------------------------------------------
// MFMA flash attention v8 (causal) - R12/R17-verified exact. Paired q-tiles
// {p, 15-p}, grid 512 (2 blocks/CU), 32x32 MFMA, in-register softmax (T12),
// triple-buffered K/V with counted vmcnt(4), raw v_exp_f32, fmaf-folded
// scale, v_max3 tree, split l-accumulators.
// ---------------------------------------------------------------------------
__global__ __launch_bounds__(256, 2) void attn_mfma8_kernel(
    const u16* __restrict__ qkvb, const u16* __restrict__ vT,
    u16* __restrict__ yb)
{
    __shared__ u16 Kb[3][64 * 64];   // [k-row][d-chunk swizzled]
    __shared__ u16 Vb[3][64 * 64];   // [d-row][k-chunk swizzled]

    const int tid = threadIdx.x;
    const int w   = tid >> 6;        // wave 0..3
    const int l   = tid & 63;
    const int q31 = l & 31;          // q (QK^T B-col) / d (PV B-col)
    const int hi  = l >> 5;
    const int work = xcd_work(blockIdx.x, 512);
    const int pr  = work & 7;        // pair index 0..7
    const int bh  = work >> 3;       // 8 bh per XCD
    const int b   = bh >> 4, h = bh & 15;

    const float S2 = 0.18033688f;    // 0.125 * log2(e)

    const u16* Kg = qkvb + (size_t)(b * Tn) * (3 * Cn) + Cn + h * HDn;
    const u16* Vg = vT + (size_t)bh * HDn * Tn;

    const int srow = l >> 3;                   // staging row 0..7
    const int schk = ((l & 7) ^ srow) << 3;    // swizzled source chunk (u16)
    const int rloc = w * 16;                   // wave's staging row slice
    const int rsw8 = q31 & 7;                  // read-side XOR key (chunk idx)

    #define STAGE_A(kt, bufi)                                                  \
        do {                                                                   \
            _Pragma("unroll")                                                  \
            for (int jc = 0; jc < 2; ++jc) {                                   \
                const int rr = rloc + jc * 8;                                  \
                GLL(Kg + (size_t)((kt) * 64 + rr + srow) * (3 * Cn) + schk,    \
                    &Kb[bufi][rr * 64]);                                       \
                GLL(Vg + (size_t)(rr + srow) * Tn + (kt) * 64 + schk,          \
                    &Vb[bufi][rr * 64]);                                       \
            }                                                                  \
        } while (0)

    #pragma unroll 1
    for (int half = 0; half < 2; ++half) {
        const int qt = half ? (15 - pr) : pr;   // 128-row tile index
        const int ktmax = 2 * qt + 2;
        const int qrow0 = qt * 128 + w * 32;    // wave's first q row
        const int qglob = qrow0 + q31;          // this lane's q row

        // Q B-frags: qf[c] = Q[qglob][c*16 + hi*8 .. +7]
        const u16* Qp = qkvb + (size_t)(b * Tn + qglob) * (3 * Cn)
                        + h * HDn + hi * 8;
        bf16x8 qf[4];
        #pragma unroll
        for (int c = 0; c < 4; ++c) qf[c] = *(const bf16x8*)(Qp + c * 16);

        f32x16 O0, O1;
        #pragma unroll
        for (int r = 0; r < 16; ++r) { O0[r] = 0.f; O1[r] = 0.f; }
        float m = -INFINITY, ls = 0.f;

        STAGE_A(0, 0);
        STAGE_A(1, 1);

        int cur = 0;
        for (int kt = 0; kt < ktmax; ++kt) {
            if (kt < ktmax - 1) WAITCNT4();
            else                WAITCNT0();
            __builtin_amdgcn_s_barrier();

            if (kt + 2 < ktmax) {
                const int nb = cur + 2 >= 3 ? cur - 1 : cur + 2;
                STAGE_A(kt + 2, nb);
            }
            const u16* Kc = Kb[cur];
            const u16* Vc = Vb[cur];

            if (kt * 64 <= qrow0 + 31) {   // wave has unmasked work
                // S^T = K Q^T : two 32x32 tiles (k 0..31, 32..63)
                f32x16 S0, S1;
                #pragma unroll
                for (int r = 0; r < 16; ++r) { S0[r] = 0.f; S1[r] = 0.f; }
                __builtin_amdgcn_s_setprio(1);
                #pragma unroll
                for (int c = 0; c < 4; ++c) {
                    const int co = ((2 * c + hi) ^ rsw8) << 3;
                    const bf16x8 k0 = *(const bf16x8*)&Kc[q31 * 64 + co];
                    const bf16x8 k1 = *(const bf16x8*)&Kc[(32 + q31) * 64 + co];
                    S0 = __builtin_amdgcn_mfma_f32_32x32x16_bf16(k0, qf[c], S0, 0, 0, 0);
                    S1 = __builtin_amdgcn_mfma_f32_32x32x16_bf16(k1, qf[c], S1, 0, 0, 0);
                }
                __builtin_amdgcn_s_setprio(0);

                // causal mask (diagonal-straddling steps only)
                if (kt * 64 + 63 > qrow0) {
                    #pragma unroll
                    for (int r = 0; r < 16; ++r) {
                        const int kl = kt * 64 + (r & 3) + 8 * (r >> 2) + 4 * hi;
                        if (kl > qglob)      S0[r] = -INFINITY;
                        if (kl + 32 > qglob) S1[r] = -INFINITY;
                    }
                }

                // row max: v_max3 tree (depth 4) + 1 cross-half shuffle
                float a0 = max3f(S0[0],  S0[1],  S0[2]);
                float a1 = max3f(S0[3],  S0[4],  S0[5]);
                float a2 = max3f(S0[6],  S0[7],  S0[8]);
                float a3 = max3f(S0[9],  S0[10], S0[11]);
                float a4 = max3f(S0[12], S0[13], S0[14]);
                float a5 = max3f(S0[15], S1[0],  S1[1]);
                float a6 = max3f(S1[2],  S1[3],  S1[4]);
                float a7 = max3f(S1[5],  S1[6],  S1[7]);
                float a8 = max3f(S1[8],  S1[9],  S1[10]);
                float a9 = max3f(S1[11], S1[12], S1[13]);
                float aA = fmaxf(S1[14], S1[15]);
                float b0 = max3f(a0, a1, a2);
                float b1 = max3f(a3, a4, a5);
                float b2 = max3f(a6, a7, a8);
                float b3 = fmaxf(a9, aA);
                float mt = fmaxf(fmaxf(b0, b1), fmaxf(b2, b3));
                mt = fmaxf(mt, __shfl_xor(mt, 32));

                // defer-max (first active step always triggers: m = -inf)
                float lscale = 1.f;
                if (__any(mt > m + 64.f)) {
                    const float mn = fmaxf(m, mt);
                    const float alpha = EXP2R((m - mn) * S2);
                    m = mn; lscale = alpha;
                    #pragma unroll
                    for (int r = 0; r < 16; ++r) {
                        const int qloc = (r & 3) + 8 * (r >> 2) + 4 * hi;
                        const float ar = __shfl(alpha, qloc);
                        O0[r] *= ar; O1[r] *= ar;
                    }
                }

                // P = exp2(S*S2 - m*S2) via fmaf + raw v_exp_f32
                const float nms2 = -m * S2;
                float lt0 = 0.f, lt1 = 0.f;
                u32 w0[8], w1[8];
                #pragma unroll
                for (int i = 0; i < 8; ++i) {
                    const float p0 = EXP2R(fmaf(S0[2 * i],     S2, nms2));
                    const float p1 = EXP2R(fmaf(S0[2 * i + 1], S2, nms2));
                    const float p2 = EXP2R(fmaf(S1[2 * i],     S2, nms2));
                    const float p3 = EXP2R(fmaf(S1[2 * i + 1], S2, nms2));
                    lt0 += (p0 + p1);
                    lt1 += (p2 + p3);
                    w0[i] = cvtpk(p0, p1);
                    w1[i] = cvtpk(p2, p3);
                }
                float lt = lt0 + lt1;
                lt += __shfl_xor(lt, 32);
                ls = ls * lscale + lt;

                // O += P @ V : assemble A-frags via permlane32_swap, B from Vs
                __builtin_amdgcn_s_setprio(1);
                #pragma unroll
                for (int t2 = 0; t2 < 2; ++t2) {
                    #pragma unroll
                    for (int c1 = 0; c1 < 2; ++c1) {
                        u32 a0w = t2 ? w1[4 * c1 + 0] : w0[4 * c1 + 0];
                        u32 b0w = t2 ? w1[4 * c1 + 2] : w0[4 * c1 + 2];
                        u32 a1w = t2 ? w1[4 * c1 + 1] : w0[4 * c1 + 1];
                        u32 b1w = t2 ? w1[4 * c1 + 3] : w0[4 * c1 + 3];
                        pswap(a0w, b0w);   // -> frag words 0 and 2
                        pswap(a1w, b1w);   // -> frag words 1 and 3
                        u32x4 fr; fr.x = a0w; fr.y = a1w; fr.z = b0w; fr.w = b1w;
                        const bf16x8 pf = __builtin_bit_cast(bf16x8, fr);
                        const int c = t2 * 2 + c1;
                        const int co = ((2 * c + hi) ^ rsw8) << 3;
                        const bf16x8 v0 = *(const bf16x8*)&Vc[q31 * 64 + co];
                        const bf16x8 v1 = *(const bf16x8*)&Vc[(32 + q31) * 64 + co];
                        O0 = __builtin_amdgcn_mfma_f32_32x32x16_bf16(pf, v0, O0, 0, 0, 0);
                        O1 = __builtin_amdgcn_mfma_f32_32x32x16_bf16(pf, v1, O1, 0, 0, 0);
                    }
                }
                __builtin_amdgcn_s_setprio(0);
            }

            cur = cur == 2 ? 0 : cur + 1;
        }

        // all waves done with LDS before next half's prologue restages
        __builtin_amdgcn_s_barrier();

        // epilogue: O row r -> q = qrow0 + (r&3)+8*(r>>2)+4*hi, col = d
        #pragma unroll
        for (int r = 0; r < 16; ++r) {
            const int qloc = (r & 3) + 8 * (r >> 2) + 4 * hi;
            const float inv = __builtin_amdgcn_rcpf(__shfl(ls, qloc));
            u16* yp = yb + (size_t)(b * Tn + qrow0 + qloc) * Cn + h * HDn + q31;
            yp[0]  = f2b(O0[r] * inv);
            yp[32] = f2b(O1[r] * inv);
        }
    }
    #undef STAGE_A
}

// ---------------------------------------------------------------------------
extern "C" void kernel_launch(void* const* d_in, const int* in_sizes, int n_in,
                              void* d_out, int out_size, void* d_ws, size_t ws_size,
                              hipStream_t stream)
{
    const float* x      = (const float*)d_in[0];
    const float* W_attn = (const float*)d_in[1];
    const float* b_attn = (const float*)d_in[2];
    const float* W_proj = (const float*)d_in[3];
    const float* b_proj = (const float*)d_in[4];
    float* out = (float*)d_out;

    // Workspace (bf16): xb | WaT | WpT | qkvb | yb | vT  (~108 MB)
    u16* xb   = (u16*)d_ws;
    u16* WaT  = xb   + (size_t)Mn * Cn;
    u16* WpT  = WaT  + (size_t)3 * Cn * Cn;
    u16* qkvb = WpT  + (size_t)Cn * Cn;
    u16* yb   = qkvb + (size_t)Mn * 3 * Cn;
    u16* vT   = yb   + (size_t)Mn * Cn;

    // one fused prep launch: x->bf16 convert + both weight transposes
    prep_kernel<<<6144, 256, 0, stream>>>(
        (const float4*)x, (ushort4*)xb, Mn * Cn / 4,
        W_attn, WaT, W_proj, WpT);

    // qkv = x @ W_attn + b_attn; Q/K -> qkvb rows, V -> vT (fused transpose)
    gemm_qkv_kernel<<<64 * 12, 256, 0, stream>>>(
        xb, WaT, b_attn, qkvb, vT, 3 * Cn, Cn, 12);

    // causal MFMA attention -> yb (bf16); grid 512 paired, XCD-grouped
    attn_mfma8_kernel<<<512, 256, 0, stream>>>(qkvb, vT, yb);

    // out = y @ W_proj + b_proj (f32 out); grid 512 (2 blocks/CU)
    gemm_proj_kernel<<<8 * 64, 256, 0, stream>>>(
        yb, WpT, b_proj, out, Cn, Cn, 8);
}